// Round 1
// baseline (927.898 us; speedup 1.0000x reference)
//
#include <hip/hip_runtime.h>

// ---------------------------------------------------------------------------
// Triplane sample + 4-layer MLP, N=1e6 points.
// Pipeline:
//   K1: transpose planes [3][32][512][512] f32 -> [3][512][512][32] f16 (x256)
//   K2: convert w0/w1/w2 -> f16
//   K3: per-point bilinear sample of 3 planes -> feats f16 [N][32] (scaled x256)
//   K4: fused MLP via mfma_f32_16x16x32_f16, computed transposed (C^T = W.H^T)
//       so all LDS traffic is contiguous b128 reads / b64 writes.
// Scale S=256 keeps everything in fp16 normal range; epilogues add S*b in fp32;
// final layer divides by S (done in fp32 VALU with fp32 w3 for precision).
// ---------------------------------------------------------------------------

#define SF 256.0f
#define HPAD 136  // halves per point-row in LDS (128 + 8 pad); 272 B, 16B-aligned

typedef _Float16 half8 __attribute__((ext_vector_type(8)));
typedef _Float16 half4_t __attribute__((ext_vector_type(4)));
typedef float f32x4 __attribute__((ext_vector_type(4)));
typedef unsigned int u32x4 __attribute__((ext_vector_type(4)));

// ---------------- K1: plane transpose+convert+scale ----------------
__global__ __launch_bounds__(256) void plane_transpose(
    const float* __restrict__ planes, _Float16* __restrict__ ph) {
  int t = blockIdx.x * 256 + threadIdx.x;     // 3*2^18 threads exactly
  int pid = t >> 18;
  int rem = t & ((1 << 18) - 1);              // y*512 + x
  const float* src = planes + ((size_t)pid << 23) + rem;  // [pid][c][y][x]
  union { _Float16 h[32]; u32x4 v[4]; } u;
#pragma unroll
  for (int c = 0; c < 32; c++)
    u.h[c] = (_Float16)(src[(size_t)c << 18] * SF);
  u32x4* dst = reinterpret_cast<u32x4*>(ph + ((size_t)t << 5));
#pragma unroll
  for (int i = 0; i < 4; i++) dst[i] = u.v[i];
}

// ---------------- K2: weight f32 -> f16 ----------------
__global__ __launch_bounds__(256) void weights_convert(
    const float* __restrict__ w0, const float* __restrict__ w1,
    const float* __restrict__ w2, _Float16* __restrict__ w0h,
    _Float16* __restrict__ w1h, _Float16* __restrict__ w2h) {
  int t = blockIdx.x * 256 + threadIdx.x;     // 36864 threads exactly
  if (t < 4096) w0h[t] = (_Float16)w0[t];
  else if (t < 20480) w1h[t - 4096] = (_Float16)w1[t - 4096];
  else w2h[t - 20480] = (_Float16)w2[t - 20480];
}

// ---------------- K3: bilinear sampling ----------------
__device__ inline void samp(const _Float16* __restrict__ pl, float X, float Y,
                            float* acc) {
  // match reference: grid_sample, padding_mode='zeros', align_corners=True
  float fx = (X + 1.0f) * 0.5f * 511.0f;
  float fy = (Y + 1.0f) * 0.5f * 511.0f;
  float x0f = floorf(fx), y0f = floorf(fy);
  float wx1 = fx - x0f, wy1 = fy - y0f;
  float wx0 = 1.0f - wx1, wy0 = 1.0f - wy1;
  int x0 = (int)x0f, y0 = (int)y0f;
  int x1 = x0 + 1, y1 = y0 + 1;
  float vx0 = (x0 >= 0 && x0 < 512) ? 1.0f : 0.0f;
  float vx1 = (x1 >= 0 && x1 < 512) ? 1.0f : 0.0f;
  float vy0 = (y0 >= 0 && y0 < 512) ? 1.0f : 0.0f;
  float vy1 = (y1 >= 0 && y1 < 512) ? 1.0f : 0.0f;
  int xc0 = min(max(x0, 0), 511), xc1 = min(max(x1, 0), 511);
  int yc0 = min(max(y0, 0), 511), yc1 = min(max(y1, 0), 511);
  float w00 = wx0 * wy0 * vx0 * vy0, w10 = wx1 * wy0 * vx1 * vy0;
  float w01 = wx0 * wy1 * vx0 * vy1, w11 = wx1 * wy1 * vx1 * vy1;
  const _Float16* p00 = pl + ((((size_t)yc0 << 9) + xc0) << 5);
  const _Float16* p10 = pl + ((((size_t)yc0 << 9) + xc1) << 5);
  const _Float16* p01 = pl + ((((size_t)yc1 << 9) + xc0) << 5);
  const _Float16* p11 = pl + ((((size_t)yc1 << 9) + xc1) << 5);
#pragma unroll
  for (int ch = 0; ch < 4; ch++) {
    union { u32x4 v; _Float16 h[8]; } a, b, c, d;
    a.v = *reinterpret_cast<const u32x4*>(p00 + ch * 8);
    b.v = *reinterpret_cast<const u32x4*>(p10 + ch * 8);
    c.v = *reinterpret_cast<const u32x4*>(p01 + ch * 8);
    d.v = *reinterpret_cast<const u32x4*>(p11 + ch * 8);
#pragma unroll
    for (int j = 0; j < 8; j++) {
      acc[ch * 8 + j] += w00 * (float)a.h[j] + w10 * (float)b.h[j] +
                         w01 * (float)c.h[j] + w11 * (float)d.h[j];
    }
  }
}

__global__ __launch_bounds__(256) void sample_kernel(
    const float* __restrict__ coords, const _Float16* __restrict__ ph,
    _Float16* __restrict__ feats, int npts) {
  int p = blockIdx.x * 256 + threadIdx.x;
  if (p >= npts) return;
  float cx = coords[3 * (size_t)p + 0];
  float cy = coords[3 * (size_t)p + 1];
  float cz = coords[3 * (size_t)p + 2];
  float acc[32];
#pragma unroll
  for (int c = 0; c < 32; c++) acc[c] = 0.0f;
  samp(ph, cx, cy, acc);                         // plane 0: (x, y)
  samp(ph + (1u << 23), cy, cz, acc);            // plane 1: (y, z)
  samp(ph + (2u << 23), cx, cz, acc);            // plane 2: (x, z)
  union { _Float16 h[32]; u32x4 v[4]; } u;
#pragma unroll
  for (int c = 0; c < 32; c++) u.h[c] = (_Float16)acc[c];
  u32x4* dst = reinterpret_cast<u32x4*>(feats + ((size_t)p << 5));
#pragma unroll
  for (int i = 0; i < 4; i++) dst[i] = u.v[i];
}

// ---------------- K4: fused MLP ----------------
__device__ inline half8 ld16(const _Float16* p) {
  return *reinterpret_cast<const half8*>(p);
}

// C^T epilogue: lane holds col=point(lane&15), rows=hidden (quad*4 + r) [m89].
// relu(acc + S*b) -> 4 contiguous f16 -> ds_write_b64 into H[point][hidden].
__device__ inline void epilogue(f32x4 (&acc)[8][4], const float* __restrict__ bias,
                                _Float16* H, int n16, int g) {
#pragma unroll
  for (int mt = 0; mt < 8; mt++) {
    f32x4 bb = *reinterpret_cast<const f32x4*>(bias + mt * 16 + g * 4);
#pragma unroll
    for (int nt = 0; nt < 4; nt++) {
      half4_t v;
#pragma unroll
      for (int r = 0; r < 4; r++) {
        float x = acc[mt][nt][r] + SF * bb[r];
        v[r] = (_Float16)fmaxf(x, 0.0f);
      }
      *reinterpret_cast<half4_t*>(&H[(nt * 16 + n16) * HPAD + mt * 16 + g * 4]) = v;
    }
  }
}

// One hidden layer, K=128: C^T = W(128x128) * H^T(128x64).
// A-frags: W rows from global (L1/L2). B-frags: H rows from LDS (fully
// preloaded into regs before epilogue overwrites H -> no WAR hazard).
__device__ inline void layer128(f32x4 (&acc)[8][4], _Float16* H,
                                const _Float16* __restrict__ Wg,
                                const float* __restrict__ bias, int n16, int g) {
  half8 B[4][4];
#pragma unroll
  for (int nt = 0; nt < 4; nt++)
#pragma unroll
    for (int ks = 0; ks < 4; ks++)
      B[nt][ks] = ld16(&H[(nt * 16 + n16) * HPAD + ks * 32 + g * 8]);
  f32x4 zero = {0.0f, 0.0f, 0.0f, 0.0f};
#pragma unroll
  for (int mt = 0; mt < 8; mt++) {
#pragma unroll
    for (int nt = 0; nt < 4; nt++) acc[mt][nt] = zero;
#pragma unroll
    for (int ks = 0; ks < 4; ks++) {
      half8 A = ld16(Wg + (mt * 16 + n16) * 128 + ks * 32 + g * 8);
#pragma unroll
      for (int nt = 0; nt < 4; nt++)
        acc[mt][nt] =
            __builtin_amdgcn_mfma_f32_16x16x32_f16(A, B[nt][ks], acc[mt][nt], 0, 0, 0);
    }
  }
  epilogue(acc, bias, H, n16, g);
}

__global__ __launch_bounds__(256, 2) void mlp_kernel(
    const _Float16* __restrict__ feats, const _Float16* __restrict__ w0h,
    const _Float16* __restrict__ w1h, const _Float16* __restrict__ w2h,
    const float* __restrict__ b0, const float* __restrict__ b1,
    const float* __restrict__ b2, const float* __restrict__ w3,
    const float* __restrict__ b3, float* __restrict__ out, int npts) {
  __shared__ alignas(16) _Float16 hbuf[4][64 * HPAD];  // 68 KB -> 2 blocks/CU
  int tid = threadIdx.x;
  int wv = tid >> 6, lane = tid & 63;
  int n16 = lane & 15, g = lane >> 4;
  long base = (long)blockIdx.x * 256 + wv * 64;  // 64 points per wave
  if (base >= npts) return;                      // no __syncthreads below: safe
  _Float16* H = hbuf[wv];
  f32x4 acc[8][4];

  // layer 0: C^T = W0(128x32) * feats^T(32x64); B-frags straight from global.
  {
    half8 B[4];
#pragma unroll
    for (int nt = 0; nt < 4; nt++)
      B[nt] = ld16(feats + (base + nt * 16 + n16) * 32 + g * 8);
    f32x4 zero = {0.0f, 0.0f, 0.0f, 0.0f};
#pragma unroll
    for (int mt = 0; mt < 8; mt++) {
      half8 A = ld16(w0h + (mt * 16 + n16) * 32 + g * 8);
#pragma unroll
      for (int nt = 0; nt < 4; nt++)
        acc[mt][nt] = __builtin_amdgcn_mfma_f32_16x16x32_f16(A, B[nt], zero, 0, 0, 0);
    }
    epilogue(acc, b0, H, n16, g);
  }

  layer128(acc, H, w1h, b1, n16, g);
  layer128(acc, H, w2h, b2, n16, g);

  // layer 3: out = dot(h2, w3)/S + b3, fp32 VALU; lane <-> point.
  float o = 0.0f;
#pragma unroll
  for (int i = 0; i < 16; i++) {
    half8 hv = ld16(&H[lane * HPAD + i * 8]);
#pragma unroll
    for (int j = 0; j < 8; j++) o += (float)hv[j] * w3[i * 8 + j];
  }
  out[base + lane] = o * (1.0f / SF) + b3[0];
}

// ---------------- launch ----------------
extern "C" void kernel_launch(void* const* d_in, const int* in_sizes, int n_in,
                              void* d_out, int out_size, void* d_ws, size_t ws_size,
                              hipStream_t stream) {
  const float* coords = (const float*)d_in[0];
  const float* planes = (const float*)d_in[1];
  const float* w0 = (const float*)d_in[2];
  const float* b0 = (const float*)d_in[3];
  const float* w1 = (const float*)d_in[4];
  const float* b1 = (const float*)d_in[5];
  const float* w2 = (const float*)d_in[6];
  const float* b2 = (const float*)d_in[7];
  const float* w3 = (const float*)d_in[8];
  const float* b3 = (const float*)d_in[9];
  float* out = (float*)d_out;
  int npts = in_sizes[0] / 3;  // 1,000,000

  // workspace layout (bytes): ph 50,331,648 | w0h 8192 | w1h 32768 | w2h 32768
  //                           | feats npts*64  => ~114.4 MB total
  char* ws = (char*)d_ws;
  _Float16* ph = (_Float16*)ws;
  _Float16* w0h = (_Float16*)(ws + 50331648);
  _Float16* w1h = (_Float16*)(ws + 50331648 + 8192);
  _Float16* w2h = (_Float16*)(ws + 50331648 + 40960);
  _Float16* feats = (_Float16*)(ws + 50331648 + 73728);

  plane_transpose<<<3072, 256, 0, stream>>>(planes, ph);
  weights_convert<<<144, 256, 0, stream>>>(w0, w1, w2, w0h, w1h, w2h);
  int blk = (npts + 255) / 256;
  sample_kernel<<<blk, 256, 0, stream>>>(coords, ph, feats, npts);
  mlp_kernel<<<blk, 256, 0, stream>>>(feats, w0h, w1h, w2h, b0, b1, b2, w3, b3,
                                      out, npts);
}

// Round 2
// 591.838 us; speedup vs baseline: 1.5678x; 1.5678x over previous
//
#include <hip/hip_runtime.h>

// ---------------------------------------------------------------------------
// Triplane sample + 4-layer MLP, N=1e6 points.
//   K0: zero histogram
//   K1: transpose planes [3][32][512][512] f32 -> [3][512][512][32] f16 (x256)
//   K2: convert w0/w1/w2 -> f16
//   K3: Morton-cell histogram (32^3 cells)
//   K4: exclusive scan (single 1024-thread block)
//   K5: scatter points into bucket order: sorted[pos] = {x,y,z,bitcast(idx)}
//   K6: bilinear sample in sorted order -> feats f16 [N][32] (scaled x256)
//   K7: fused MLP (mfma f16, transposed C^T = W.H^T); out[orig_idx] = result
// Scale S=256 keeps f16 in normal range; epilogues add S*b in fp32; final
// layer divides by S in fp32.
// ---------------------------------------------------------------------------

#define SF 256.0f
#define HPAD 136  // halves per point-row in LDS (128 + 8 pad)

typedef _Float16 half8 __attribute__((ext_vector_type(8)));
typedef _Float16 half4_t __attribute__((ext_vector_type(4)));
typedef float f32x4 __attribute__((ext_vector_type(4)));
typedef unsigned int u32x4 __attribute__((ext_vector_type(4)));

// ---------------- K0: zero histogram ----------------
__global__ __launch_bounds__(256) void zero_hist(unsigned* __restrict__ hist) {
  int t = blockIdx.x * 256 + threadIdx.x;
  if (t < 32768) hist[t] = 0u;
}

// ---------------- K1: plane transpose+convert+scale ----------------
__global__ __launch_bounds__(256) void plane_transpose(
    const float* __restrict__ planes, _Float16* __restrict__ ph) {
  int t = blockIdx.x * 256 + threadIdx.x;     // 3*2^18 threads exactly
  int pid = t >> 18;
  int rem = t & ((1 << 18) - 1);              // y*512 + x
  const float* src = planes + ((size_t)pid << 23) + rem;  // [pid][c][y][x]
  union { _Float16 h[32]; u32x4 v[4]; } u;
#pragma unroll
  for (int c = 0; c < 32; c++)
    u.h[c] = (_Float16)(src[(size_t)c << 18] * SF);
  u32x4* dst = reinterpret_cast<u32x4*>(ph + ((size_t)t << 5));
#pragma unroll
  for (int i = 0; i < 4; i++) dst[i] = u.v[i];
}

// ---------------- K2: weight f32 -> f16 ----------------
__global__ __launch_bounds__(256) void weights_convert(
    const float* __restrict__ w0, const float* __restrict__ w1,
    const float* __restrict__ w2, _Float16* __restrict__ w0h,
    _Float16* __restrict__ w1h, _Float16* __restrict__ w2h) {
  int t = blockIdx.x * 256 + threadIdx.x;     // 36864 threads exactly
  if (t < 4096) w0h[t] = (_Float16)w0[t];
  else if (t < 20480) w1h[t - 4096] = (_Float16)w1[t - 4096];
  else w2h[t - 20480] = (_Float16)w2[t - 20480];
}

// ---------------- Morton key ----------------
__device__ inline unsigned spread5(unsigned v) {
  v &= 31u;
  v = (v | (v << 8)) & 0x100Fu;
  v = (v | (v << 4)) & 0x10C3u;
  v = (v | (v << 2)) & 0x1249u;
  return v;
}
__device__ inline unsigned cellkey(float x, float y, float z) {
  int qx = min(31, max(0, (int)((x + 1.0f) * 16.0f)));
  int qy = min(31, max(0, (int)((y + 1.0f) * 16.0f)));
  int qz = min(31, max(0, (int)((z + 1.0f) * 16.0f)));
  return spread5((unsigned)qx) | (spread5((unsigned)qy) << 1) |
         (spread5((unsigned)qz) << 2);
}

// ---------------- K3: histogram ----------------
__global__ __launch_bounds__(256) void hist_kernel(
    const float* __restrict__ coords, unsigned* __restrict__ hist, int npts) {
  int p = blockIdx.x * 256 + threadIdx.x;
  if (p >= npts) return;
  float x = coords[3 * (size_t)p + 0];
  float y = coords[3 * (size_t)p + 1];
  float z = coords[3 * (size_t)p + 2];
  atomicAdd(&hist[cellkey(x, y, z)], 1u);
}

// ---------------- K4: exclusive scan of 32768 counts ----------------
__global__ __launch_bounds__(1024) void scan_kernel(
    const unsigned* __restrict__ hist, unsigned* __restrict__ cursor) {
  __shared__ unsigned sums[1024];
  int t = threadIdx.x;
  unsigned local[32];
  unsigned s = 0;
#pragma unroll
  for (int i = 0; i < 32; i++) { local[i] = hist[t * 32 + i]; s += local[i]; }
  sums[t] = s;
  __syncthreads();
  for (int off = 1; off < 1024; off <<= 1) {
    unsigned v = (t >= off) ? sums[t - off] : 0u;
    __syncthreads();
    sums[t] += v;
    __syncthreads();
  }
  unsigned base = (t == 0) ? 0u : sums[t - 1];
#pragma unroll
  for (int i = 0; i < 32; i++) { cursor[t * 32 + i] = base; base += local[i]; }
}

// ---------------- K5: scatter into bucket order ----------------
__global__ __launch_bounds__(256) void scatter_kernel(
    const float* __restrict__ coords, unsigned* __restrict__ cursor,
    float4* __restrict__ sorted, int npts) {
  int p = blockIdx.x * 256 + threadIdx.x;
  if (p >= npts) return;
  float x = coords[3 * (size_t)p + 0];
  float y = coords[3 * (size_t)p + 1];
  float z = coords[3 * (size_t)p + 2];
  unsigned pos = atomicAdd(&cursor[cellkey(x, y, z)], 1u);
  float4 v;
  v.x = x; v.y = y; v.z = z; v.w = __uint_as_float((unsigned)p);
  sorted[pos] = v;
}

// ---------------- K6: bilinear sampling ----------------
__device__ inline void samp(const _Float16* __restrict__ pl, float X, float Y,
                            float* acc) {
  float fx = (X + 1.0f) * 0.5f * 511.0f;
  float fy = (Y + 1.0f) * 0.5f * 511.0f;
  float x0f = floorf(fx), y0f = floorf(fy);
  float wx1 = fx - x0f, wy1 = fy - y0f;
  float wx0 = 1.0f - wx1, wy0 = 1.0f - wy1;
  int x0 = (int)x0f, y0 = (int)y0f;
  int x1 = x0 + 1, y1 = y0 + 1;
  float vx0 = (x0 >= 0 && x0 < 512) ? 1.0f : 0.0f;
  float vx1 = (x1 >= 0 && x1 < 512) ? 1.0f : 0.0f;
  float vy0 = (y0 >= 0 && y0 < 512) ? 1.0f : 0.0f;
  float vy1 = (y1 >= 0 && y1 < 512) ? 1.0f : 0.0f;
  int xc0 = min(max(x0, 0), 511), xc1 = min(max(x1, 0), 511);
  int yc0 = min(max(y0, 0), 511), yc1 = min(max(y1, 0), 511);
  float w00 = wx0 * wy0 * vx0 * vy0, w10 = wx1 * wy0 * vx1 * vy0;
  float w01 = wx0 * wy1 * vx0 * vy1, w11 = wx1 * wy1 * vx1 * vy1;
  const _Float16* p00 = pl + ((((size_t)yc0 << 9) + xc0) << 5);
  const _Float16* p10 = pl + ((((size_t)yc0 << 9) + xc1) << 5);
  const _Float16* p01 = pl + ((((size_t)yc1 << 9) + xc0) << 5);
  const _Float16* p11 = pl + ((((size_t)yc1 << 9) + xc1) << 5);
#pragma unroll
  for (int ch = 0; ch < 4; ch++) {
    union { u32x4 v; _Float16 h[8]; } a, b, c, d;
    a.v = *reinterpret_cast<const u32x4*>(p00 + ch * 8);
    b.v = *reinterpret_cast<const u32x4*>(p10 + ch * 8);
    c.v = *reinterpret_cast<const u32x4*>(p01 + ch * 8);
    d.v = *reinterpret_cast<const u32x4*>(p11 + ch * 8);
#pragma unroll
    for (int j = 0; j < 8; j++) {
      acc[ch * 8 + j] += w00 * (float)a.h[j] + w10 * (float)b.h[j] +
                         w01 * (float)c.h[j] + w11 * (float)d.h[j];
    }
  }
}

__global__ __launch_bounds__(256) void sample_kernel(
    const float* __restrict__ coords, const float4* __restrict__ sorted,
    const _Float16* __restrict__ ph, _Float16* __restrict__ feats, int npts,
    int use_sorted) {
  // XCD swizzle: give each XCD a contiguous Morton range for L2 locality.
  int nb = gridDim.x, bid = blockIdx.x;
  int per = nb >> 3;
  int sb = (bid < (per << 3)) ? ((bid & 7) * per + (bid >> 3)) : bid;
  int p = sb * 256 + threadIdx.x;
  if (p >= npts) return;
  float cx, cy, cz;
  if (use_sorted) {
    float4 f = sorted[p];
    cx = f.x; cy = f.y; cz = f.z;
  } else {
    cx = coords[3 * (size_t)p + 0];
    cy = coords[3 * (size_t)p + 1];
    cz = coords[3 * (size_t)p + 2];
  }
  float acc[32];
#pragma unroll
  for (int c = 0; c < 32; c++) acc[c] = 0.0f;
  samp(ph, cx, cy, acc);                         // plane 0: (x, y)
  samp(ph + (1u << 23), cy, cz, acc);            // plane 1: (y, z)
  samp(ph + (2u << 23), cx, cz, acc);            // plane 2: (x, z)
  union { _Float16 h[32]; u32x4 v[4]; } u;
#pragma unroll
  for (int c = 0; c < 32; c++) u.h[c] = (_Float16)acc[c];
  u32x4* dst = reinterpret_cast<u32x4*>(feats + ((size_t)p << 5));
#pragma unroll
  for (int i = 0; i < 4; i++) dst[i] = u.v[i];
}

// ---------------- K7: fused MLP ----------------
__device__ inline half8 ld16(const _Float16* p) {
  return *reinterpret_cast<const half8*>(p);
}

// C^T epilogue: lane holds col=point(lane&15), rows=hidden (quad*4 + r) [m89].
__device__ inline void epilogue(f32x4 (&acc)[8][4], const float* __restrict__ bias,
                                _Float16* H, int n16, int g) {
#pragma unroll
  for (int mt = 0; mt < 8; mt++) {
    f32x4 bb = *reinterpret_cast<const f32x4*>(bias + mt * 16 + g * 4);
#pragma unroll
    for (int nt = 0; nt < 4; nt++) {
      half4_t v;
#pragma unroll
      for (int r = 0; r < 4; r++) {
        float x = acc[mt][nt][r] + SF * bb[r];
        v[r] = (_Float16)fmaxf(x, 0.0f);
      }
      *reinterpret_cast<half4_t*>(&H[(nt * 16 + n16) * HPAD + mt * 16 + g * 4]) = v;
    }
  }
}

__device__ inline void layer128(f32x4 (&acc)[8][4], _Float16* H,
                                const _Float16* __restrict__ Wg,
                                const float* __restrict__ bias, int n16, int g) {
  half8 B[4][4];
#pragma unroll
  for (int nt = 0; nt < 4; nt++)
#pragma unroll
    for (int ks = 0; ks < 4; ks++)
      B[nt][ks] = ld16(&H[(nt * 16 + n16) * HPAD + ks * 32 + g * 8]);
  f32x4 zero = {0.0f, 0.0f, 0.0f, 0.0f};
#pragma unroll
  for (int mt = 0; mt < 8; mt++) {
#pragma unroll
    for (int nt = 0; nt < 4; nt++) acc[mt][nt] = zero;
#pragma unroll
    for (int ks = 0; ks < 4; ks++) {
      half8 A = ld16(Wg + (mt * 16 + n16) * 128 + ks * 32 + g * 8);
#pragma unroll
      for (int nt = 0; nt < 4; nt++)
        acc[mt][nt] =
            __builtin_amdgcn_mfma_f32_16x16x32_f16(A, B[nt][ks], acc[mt][nt], 0, 0, 0);
    }
  }
  epilogue(acc, bias, H, n16, g);
}

__global__ __launch_bounds__(256, 2) void mlp_kernel(
    const _Float16* __restrict__ feats, const float4* __restrict__ sorted,
    const _Float16* __restrict__ w0h, const _Float16* __restrict__ w1h,
    const _Float16* __restrict__ w2h, const float* __restrict__ b0,
    const float* __restrict__ b1, const float* __restrict__ b2,
    const float* __restrict__ w3, const float* __restrict__ b3,
    float* __restrict__ out, int npts, int use_sorted) {
  __shared__ alignas(16) _Float16 hbuf[4][64 * HPAD];  // 68 KB -> 2 blocks/CU
  int tid = threadIdx.x;
  int wv = tid >> 6, lane = tid & 63;
  int n16 = lane & 15, g = lane >> 4;
  long base = (long)blockIdx.x * 256 + wv * 64;  // 64 points per wave
  if (base >= npts) return;                      // no __syncthreads below: safe
  _Float16* H = hbuf[wv];
  f32x4 acc[8][4];

  // layer 0: C^T = W0(128x32) * feats^T(32x64)
  {
    half8 B[4];
#pragma unroll
    for (int nt = 0; nt < 4; nt++)
      B[nt] = ld16(feats + (base + nt * 16 + n16) * 32 + g * 8);
    f32x4 zero = {0.0f, 0.0f, 0.0f, 0.0f};
#pragma unroll
    for (int mt = 0; mt < 8; mt++) {
      half8 A = ld16(w0h + (mt * 16 + n16) * 32 + g * 8);
#pragma unroll
      for (int nt = 0; nt < 4; nt++)
        acc[mt][nt] = __builtin_amdgcn_mfma_f32_16x16x32_f16(A, B[nt], zero, 0, 0, 0);
    }
    epilogue(acc, b0, H, n16, g);
  }

  layer128(acc, H, w1h, b1, n16, g);
  layer128(acc, H, w2h, b2, n16, g);

  // layer 3: out = dot(h2, w3)/S + b3, fp32 VALU; lane <-> point.
  float o = 0.0f;
#pragma unroll
  for (int i = 0; i < 16; i++) {
    half8 hv = ld16(&H[lane * HPAD + i * 8]);
#pragma unroll
    for (int j = 0; j < 8; j++) o += (float)hv[j] * w3[i * 8 + j];
  }
  unsigned idx = use_sorted ? __float_as_uint(sorted[base + lane].w)
                            : (unsigned)(base + lane);
  out[idx] = o * (1.0f / SF) + b3[0];
}

// ---------------- launch ----------------
extern "C" void kernel_launch(void* const* d_in, const int* in_sizes, int n_in,
                              void* d_out, int out_size, void* d_ws, size_t ws_size,
                              hipStream_t stream) {
  const float* coords = (const float*)d_in[0];
  const float* planes = (const float*)d_in[1];
  const float* w0 = (const float*)d_in[2];
  const float* b0 = (const float*)d_in[3];
  const float* w1 = (const float*)d_in[4];
  const float* b1 = (const float*)d_in[5];
  const float* w2 = (const float*)d_in[6];
  const float* b2 = (const float*)d_in[7];
  const float* w3 = (const float*)d_in[8];
  const float* b3 = (const float*)d_in[9];
  float* out = (float*)d_out;
  int npts = in_sizes[0] / 3;  // 1,000,000

  // workspace layout (bytes):
  //   ph      @ 0          50,331,648
  //   w0h     @ 50331648   8,192
  //   w1h     @ 50339840   32,768
  //   w2h     @ 50372608   32,768
  //   hist    @ 50405376   131,072
  //   cursor  @ 50536448   131,072
  //   sorted  @ 50667520   npts*16
  //   feats   @ 50667520+npts*16   npts*64
  char* ws = (char*)d_ws;
  _Float16* ph = (_Float16*)ws;
  _Float16* w0h = (_Float16*)(ws + 50331648);
  _Float16* w1h = (_Float16*)(ws + 50339840);
  _Float16* w2h = (_Float16*)(ws + 50372608);
  unsigned* hist = (unsigned*)(ws + 50405376);
  unsigned* cursor = (unsigned*)(ws + 50536448);
  float4* sorted = (float4*)(ws + 50667520);
  size_t need = 50667520 + (size_t)npts * 16 + (size_t)npts * 64;
  int use_sorted = (ws_size == 0 || ws_size >= need) ? 1 : 0;
  _Float16* feats = use_sorted
                        ? (_Float16*)(ws + 50667520 + (size_t)npts * 16)
                        : (_Float16*)(ws + 50667520);

  int blk = (npts + 255) / 256;
  plane_transpose<<<3072, 256, 0, stream>>>(planes, ph);
  weights_convert<<<144, 256, 0, stream>>>(w0, w1, w2, w0h, w1h, w2h);
  if (use_sorted) {
    zero_hist<<<128, 256, 0, stream>>>(hist);
    hist_kernel<<<blk, 256, 0, stream>>>(coords, hist, npts);
    scan_kernel<<<1, 1024, 0, stream>>>(hist, cursor);
    scatter_kernel<<<blk, 256, 0, stream>>>(coords, cursor, sorted, npts);
  }
  sample_kernel<<<blk, 256, 0, stream>>>(coords, sorted, ph, feats, npts,
                                         use_sorted);
  mlp_kernel<<<blk, 256, 0, stream>>>(feats, sorted, w0h, w1h, w2h, b0, b1, b2,
                                      w3, b3, out, npts, use_sorted);
}